// Round 1
// baseline (26289.062 us; speedup 1.0000x reference)
//
#include <hip/hip_runtime.h>
#include <hip/hip_fp16.h>

#define T_LEN 1024
#define B_SZ  32
#define D_IN  768
#define H_SZ  768
#define G4    3072   // 4*H

// ---------------------------------------------------------------------------
// Phase A: xg[(t*32+b)][g] = hidden[b][t][:] . W_ih[g][:] + b_ih[g] + b_hh[g]
// fp32 SGEMM, 128x128 block, 8x8 microtile (split 4+4), output stored as fp16.
// ---------------------------------------------------------------------------
__global__ __launch_bounds__(256)
void xg_gemm(const float* __restrict__ hidden, const float* __restrict__ W_ih,
             const float* __restrict__ b_ih, const float* __restrict__ b_hh,
             __half* __restrict__ xg)
{
    __shared__ float As[8 * 128];
    __shared__ float Bs[8 * 128];
    const int tid = threadIdx.x;
    const int tx = tid & 15, ty = tid >> 4;
    const int n0 = blockIdx.x * 128;
    const int m0 = blockIdx.y * 128;

    const int lrow = tid >> 1;          // 0..127
    const int lk   = (tid & 1) * 4;     // 0 or 4

    // A row (m -> (t,b) permutation): m = t*32 + b
    const int m  = m0 + lrow;
    const int bb = m & 31;
    const int tt = m >> 5;
    const float* arow = hidden + ((size_t)bb * T_LEN + tt) * D_IN;
    const float* brow = W_ih + (size_t)(n0 + lrow) * D_IN;

    float acc[8][8];
#pragma unroll
    for (int i = 0; i < 8; ++i)
#pragma unroll
        for (int j = 0; j < 8; ++j) acc[i][j] = 0.f;

    for (int kb = 0; kb < D_IN; kb += 8) {
        const float4 av = *(const float4*)(arow + kb + lk);
        const float4 bv = *(const float4*)(brow + kb + lk);
        __syncthreads();                 // previous-iter LDS reads done
        As[(lk + 0) * 128 + lrow] = av.x;
        As[(lk + 1) * 128 + lrow] = av.y;
        As[(lk + 2) * 128 + lrow] = av.z;
        As[(lk + 3) * 128 + lrow] = av.w;
        Bs[(lk + 0) * 128 + lrow] = bv.x;
        Bs[(lk + 1) * 128 + lrow] = bv.y;
        Bs[(lk + 2) * 128 + lrow] = bv.z;
        Bs[(lk + 3) * 128 + lrow] = bv.w;
        __syncthreads();
#pragma unroll
        for (int k = 0; k < 8; ++k) {
            const float4 a0 = *(const float4*)&As[k * 128 + 4 * ty];
            const float4 a1 = *(const float4*)&As[k * 128 + 64 + 4 * ty];
            const float4 b0 = *(const float4*)&Bs[k * 128 + 4 * tx];
            const float4 b1 = *(const float4*)&Bs[k * 128 + 64 + 4 * tx];
            const float a[8] = {a0.x, a0.y, a0.z, a0.w, a1.x, a1.y, a1.z, a1.w};
            const float b[8] = {b0.x, b0.y, b0.z, b0.w, b1.x, b1.y, b1.z, b1.w};
#pragma unroll
            for (int i = 0; i < 8; ++i)
#pragma unroll
                for (int j = 0; j < 8; ++j)
                    acc[i][j] = fmaf(a[i], b[j], acc[i][j]);
        }
    }

    // bias (b_ih + b_hh), added once here
    float bias[8];
    {
        const int n_lo = n0 + 4 * tx, n_hi = n0 + 64 + 4 * tx;
        const float4 bi0 = *(const float4*)(b_ih + n_lo);
        const float4 bh0 = *(const float4*)(b_hh + n_lo);
        const float4 bi1 = *(const float4*)(b_ih + n_hi);
        const float4 bh1 = *(const float4*)(b_hh + n_hi);
        bias[0] = bi0.x + bh0.x; bias[1] = bi0.y + bh0.y;
        bias[2] = bi0.z + bh0.z; bias[3] = bi0.w + bh0.w;
        bias[4] = bi1.x + bh1.x; bias[5] = bi1.y + bh1.y;
        bias[6] = bi1.z + bh1.z; bias[7] = bi1.w + bh1.w;
    }

#pragma unroll
    for (int i = 0; i < 8; ++i) {
        const int mm = m0 + ((i < 4) ? (4 * ty + i) : (64 + 4 * ty + (i - 4)));
        const size_t base = (size_t)mm * G4;
        const int n_lo = n0 + 4 * tx, n_hi = n0 + 64 + 4 * tx;
        __half2 p0 = __halves2half2(__float2half_rn(acc[i][0] + bias[0]),
                                    __float2half_rn(acc[i][1] + bias[1]));
        __half2 p1 = __halves2half2(__float2half_rn(acc[i][2] + bias[2]),
                                    __float2half_rn(acc[i][3] + bias[3]));
        __half2 p2 = __halves2half2(__float2half_rn(acc[i][4] + bias[4]),
                                    __float2half_rn(acc[i][5] + bias[5]));
        __half2 p3 = __halves2half2(__float2half_rn(acc[i][6] + bias[6]),
                                    __float2half_rn(acc[i][7] + bias[7]));
        *(__half2*)(xg + base + n_lo)     = p0;
        *(__half2*)(xg + base + n_lo + 2) = p1;
        *(__half2*)(xg + base + n_hi)     = p2;
        *(__half2*)(xg + base + n_hi + 2) = p3;
    }
}

// ---------------------------------------------------------------------------
// Zero the per-step sync counters (ws is poisoned 0xAA before every launch).
// ---------------------------------------------------------------------------
__global__ void zero_cnt(unsigned* cnt) {
    cnt[blockIdx.x * 1024 + threadIdx.x] = 0u;
}

// ---------------------------------------------------------------------------
// Phase B: persistent cooperative recurrence.
// 256 WGs (1/CU). WG = (r, c): r in [0,128) owns 6 hidden units (24 gate rows
// of W_hh resident in LDS for all 1024 steps), c in {0,1} picks a 16-batch
// group. Two independent sync domains of 128 WGs (batches are independent).
// Per step: wait(cnt[t-1][c]==128) -> acquire -> stage h_prev (16x768) to LDS
// -> 12x4 register-tile dot with 32-way K-split -> LDS reduce -> gates ->
// write h to d_out -> release -> atomicAdd(cnt[t][c]).
// c-state lives in registers of the 96 combine threads (same thread, same
// (unit,batch) every step).
// ---------------------------------------------------------------------------
__global__ void __launch_bounds__(256, 1)
lstm_rec(const __half* __restrict__ xg, const float* __restrict__ Whh,
         float* __restrict__ out, unsigned* __restrict__ cnt)
{
    extern __shared__ float sm[];
    float* Wsl = sm;                         // 24*768 = 18432 floats
    float* hsl = sm + 24 * H_SZ;             // 12288 floats (union with P)
    float* G   = sm + 24 * H_SZ + 12288;     // 384 floats

    const int tid = threadIdx.x;
    const int wg  = blockIdx.x;
    const int c   = wg & 1;        // batch group
    const int r   = wg >> 1;       // unit group 0..127
    const int u0  = r * 6;
    const int b0  = c * 16;

    // ---- load W_hh slice once: rows (gate*768 + u0 + j), gate<4, j<6 ----
    for (int i = tid; i < 24 * 192; i += 256) {
        const int rr = i / 192;              // local row 0..23
        const int kc = (i % 192) * 4;
        const int gate = rr / 6, j = rr % 6;
        const float4 v = *(const float4*)&Whh[(size_t)(gate * H_SZ + u0 + j) * H_SZ + kc];
        *(float4*)&Wsl[rr * H_SZ + kc] = v;
    }

    // dot-phase role
    const int ks     = tid & 31;             // K segment (k = 4*ks + 128*jj)
    const int tileId = tid >> 5;             // 0..7
    const int tr = (tileId & 1) * 12;        // row tile base
    const int tb = (tileId >> 1) * 4;        // batch tile base

    // combine-phase role (threads 0..95)
    const int cj = tid % 6;                  // unit within group
    const int cb = tid / 6;                  // batch within group
    float c_reg = 0.f;                       // cell state, register-resident

    __syncthreads();

    for (int t = 0; t < T_LEN; ++t) {
        if (t == 0) {
            for (int i = tid; i < 384; i += 256) G[i] = 0.f;  // h_prev = 0
            __syncthreads();
        } else {
            // ---- wait for step t-1 of our batch group ----
            if (tid == 0) {
                while (__hip_atomic_load(&cnt[(t - 1) * 2 + c], __ATOMIC_RELAXED,
                                         __HIP_MEMORY_SCOPE_AGENT) < 128u) {}
            }
            __syncthreads();
            __builtin_amdgcn_fence(__ATOMIC_ACQUIRE, "agent");  // all waves invalidate

            // ---- stage h_prev[b0..b0+16][:] into LDS ----
            for (int i = tid; i < 16 * 192; i += 256) {
                const int b  = i / 192;
                const int kc = (i % 192) * 4;
                const float4 v = *(const float4*)&out[((size_t)(b0 + b) * T_LEN + (t - 1)) * H_SZ + kc];
                *(float4*)&hsl[b * H_SZ + kc] = v;
            }
            __syncthreads();

            // ---- dot: acc[12 rows][4 batches] over 24-element K segment ----
            float acc[12][4];
#pragma unroll
            for (int a = 0; a < 12; ++a)
#pragma unroll
                for (int q = 0; q < 4; ++q) acc[a][q] = 0.f;

            for (int jj = 0; jj < 6; ++jj) {
                const int k = ks * 4 + jj * 128;   // lanes stride-1 in k: conflict-free b128
                float4 hv[4];
#pragma unroll
                for (int q = 0; q < 4; ++q)
                    hv[q] = *(const float4*)&hsl[(tb + q) * H_SZ + k];
#pragma unroll
                for (int a = 0; a < 12; ++a) {
                    const float4 wv = *(const float4*)&Wsl[(tr + a) * H_SZ + k];
#pragma unroll
                    for (int q = 0; q < 4; ++q) {
                        acc[a][q] = fmaf(wv.x, hv[q].x, acc[a][q]);
                        acc[a][q] = fmaf(wv.y, hv[q].y, acc[a][q]);
                        acc[a][q] = fmaf(wv.z, hv[q].z, acc[a][q]);
                        acc[a][q] = fmaf(wv.w, hv[q].w, acc[a][q]);
                    }
                }
            }
            __syncthreads();                 // hsl reads done -> reuse as P

            // ---- write partials P[out 0..383][ks 0..31] ----
            float* P = hsl;
#pragma unroll
            for (int a = 0; a < 12; ++a)
#pragma unroll
                for (int q = 0; q < 4; ++q)
                    P[((tr + a) * 16 + (tb + q)) * 32 + ks] = acc[a][q];
            __syncthreads();

            // ---- reduce (diagonal reads: bank-conflict-free) ----
            for (int oi = tid; oi < 384; oi += 256) {
                float s = 0.f;
#pragma unroll
                for (int kk = 0; kk < 32; ++kk) {
                    const int k2 = (kk + oi) & 31;
                    s += P[oi * 32 + k2];
                }
                G[oi] = s;
            }
            __syncthreads();
        }

        // ---- gate combine: threads 0..95, one (unit, batch) each ----
        if (tid < 96) {
            const size_t xbase = ((size_t)t * B_SZ + (b0 + cb)) * G4 + u0 + cj;
            const float pi = G[(0 * 6 + cj) * 16 + cb] + __half2float(xg[xbase + 0 * H_SZ]);
            const float pf = G[(1 * 6 + cj) * 16 + cb] + __half2float(xg[xbase + 1 * H_SZ]);
            const float pg = G[(2 * 6 + cj) * 16 + cb] + __half2float(xg[xbase + 2 * H_SZ]);
            const float po = G[(3 * 6 + cj) * 16 + cb] + __half2float(xg[xbase + 3 * H_SZ]);
            const float ig = 1.f / (1.f + __expf(-pi));
            const float fg = 1.f / (1.f + __expf(-pf));
            const float gg = tanhf(pg);
            const float og = 1.f / (1.f + __expf(-po));
            c_reg = fg * c_reg + ig * gg;
            const float h = og * tanhf(c_reg);
            out[((size_t)(b0 + cb) * T_LEN + t) * H_SZ + u0 + cj] = h;
        }
        __syncthreads();                     // all h stores drained (vmcnt(0) in barrier)

        if (tid == 0) {
            __builtin_amdgcn_fence(__ATOMIC_RELEASE, "agent");   // L2 writeback
            __hip_atomic_fetch_add(&cnt[t * 2 + c], 1u, __ATOMIC_RELAXED,
                                   __HIP_MEMORY_SCOPE_AGENT);
        }
    }
}

// ---------------------------------------------------------------------------
extern "C" void kernel_launch(void* const* d_in, const int* in_sizes, int n_in,
                              void* d_out, int out_size, void* d_ws, size_t ws_size,
                              hipStream_t stream)
{
    (void)in_sizes; (void)n_in; (void)out_size; (void)ws_size;
    const float* hidden = (const float*)d_in[0];
    const float* W_ih   = (const float*)d_in[1];
    const float* W_hh   = (const float*)d_in[2];
    const float* b_ih   = (const float*)d_in[3];
    const float* b_hh   = (const float*)d_in[4];
    float* out = (float*)d_out;

    __half* xg = (__half*)d_ws;                                  // 201,326,592 B
    unsigned* cnt = (unsigned*)((char*)d_ws +
                    (size_t)T_LEN * B_SZ * G4 * sizeof(__half)); // 2048 u32

    zero_cnt<<<dim3(2), dim3(1024), 0, stream>>>(cnt);
    xg_gemm<<<dim3(G4 / 128, (B_SZ * T_LEN) / 128), dim3(256), 0, stream>>>(
        hidden, W_ih, b_ih, b_hh, xg);

    const int smem = (24 * H_SZ + 12288 + 384) * (int)sizeof(float);  // 124,416 B
    hipFuncSetAttribute((const void*)lstm_rec,
                        hipFuncAttributeMaxDynamicSharedMemorySize, smem);
    void* args[] = { (void*)&xg, (void*)&W_hh, (void*)&out, (void*)&cnt };
    hipLaunchCooperativeKernel((void*)lstm_rec, dim3(256), dim3(256),
                               args, (unsigned)smem, stream);
}

// Round 2
// 18685.451 us; speedup vs baseline: 1.4069x; 1.4069x over previous
//
#include <hip/hip_runtime.h>
#include <hip/hip_fp16.h>

#define T_LEN 1024
#define B_SZ  32
#define D_IN  768
#define H_SZ  768
#define G4    3072   // 4*H

// ---------------------------------------------------------------------------
// Phase A: xg[(t*32+b)][g] = hidden[b][t][:] . W_ih[g][:] + b_ih[g] + b_hh[g]
// fp32 SGEMM, 128x128 block, 8x8 microtile (split 4+4), output stored as fp16.
// (~2.0 ms measured in R1 — not the bottleneck; untouched this round.)
// ---------------------------------------------------------------------------
__global__ __launch_bounds__(256)
void xg_gemm(const float* __restrict__ hidden, const float* __restrict__ W_ih,
             const float* __restrict__ b_ih, const float* __restrict__ b_hh,
             __half* __restrict__ xg)
{
    __shared__ float As[8 * 128];
    __shared__ float Bs[8 * 128];
    const int tid = threadIdx.x;
    const int tx = tid & 15, ty = tid >> 4;
    const int n0 = blockIdx.x * 128;
    const int m0 = blockIdx.y * 128;

    const int lrow = tid >> 1;          // 0..127
    const int lk   = (tid & 1) * 4;     // 0 or 4

    // A row (m -> (t,b) permutation): m = t*32 + b
    const int m  = m0 + lrow;
    const int bb = m & 31;
    const int tt = m >> 5;
    const float* arow = hidden + ((size_t)bb * T_LEN + tt) * D_IN;
    const float* brow = W_ih + (size_t)(n0 + lrow) * D_IN;

    float acc[8][8];
#pragma unroll
    for (int i = 0; i < 8; ++i)
#pragma unroll
        for (int j = 0; j < 8; ++j) acc[i][j] = 0.f;

    for (int kb = 0; kb < D_IN; kb += 8) {
        const float4 av = *(const float4*)(arow + kb + lk);
        const float4 bv = *(const float4*)(brow + kb + lk);
        __syncthreads();                 // previous-iter LDS reads done
        As[(lk + 0) * 128 + lrow] = av.x;
        As[(lk + 1) * 128 + lrow] = av.y;
        As[(lk + 2) * 128 + lrow] = av.z;
        As[(lk + 3) * 128 + lrow] = av.w;
        Bs[(lk + 0) * 128 + lrow] = bv.x;
        Bs[(lk + 1) * 128 + lrow] = bv.y;
        Bs[(lk + 2) * 128 + lrow] = bv.z;
        Bs[(lk + 3) * 128 + lrow] = bv.w;
        __syncthreads();
#pragma unroll
        for (int k = 0; k < 8; ++k) {
            const float4 a0 = *(const float4*)&As[k * 128 + 4 * ty];
            const float4 a1 = *(const float4*)&As[k * 128 + 64 + 4 * ty];
            const float4 b0 = *(const float4*)&Bs[k * 128 + 4 * tx];
            const float4 b1 = *(const float4*)&Bs[k * 128 + 64 + 4 * tx];
            const float a[8] = {a0.x, a0.y, a0.z, a0.w, a1.x, a1.y, a1.z, a1.w};
            const float b[8] = {b0.x, b0.y, b0.z, b0.w, b1.x, b1.y, b1.z, b1.w};
#pragma unroll
            for (int i = 0; i < 8; ++i)
#pragma unroll
                for (int j = 0; j < 8; ++j)
                    acc[i][j] = fmaf(a[i], b[j], acc[i][j]);
        }
    }

    float bias[8];
    {
        const int n_lo = n0 + 4 * tx, n_hi = n0 + 64 + 4 * tx;
        const float4 bi0 = *(const float4*)(b_ih + n_lo);
        const float4 bh0 = *(const float4*)(b_hh + n_lo);
        const float4 bi1 = *(const float4*)(b_ih + n_hi);
        const float4 bh1 = *(const float4*)(b_hh + n_hi);
        bias[0] = bi0.x + bh0.x; bias[1] = bi0.y + bh0.y;
        bias[2] = bi0.z + bh0.z; bias[3] = bi0.w + bh0.w;
        bias[4] = bi1.x + bh1.x; bias[5] = bi1.y + bh1.y;
        bias[6] = bi1.z + bh1.z; bias[7] = bi1.w + bh1.w;
    }

#pragma unroll
    for (int i = 0; i < 8; ++i) {
        const int mm = m0 + ((i < 4) ? (4 * ty + i) : (64 + 4 * ty + (i - 4)));
        const size_t base = (size_t)mm * G4;
        const int n_lo = n0 + 4 * tx, n_hi = n0 + 64 + 4 * tx;
        __half2 p0 = __halves2half2(__float2half_rn(acc[i][0] + bias[0]),
                                    __float2half_rn(acc[i][1] + bias[1]));
        __half2 p1 = __halves2half2(__float2half_rn(acc[i][2] + bias[2]),
                                    __float2half_rn(acc[i][3] + bias[3]));
        __half2 p2 = __halves2half2(__float2half_rn(acc[i][4] + bias[4]),
                                    __float2half_rn(acc[i][5] + bias[5]));
        __half2 p3 = __halves2half2(__float2half_rn(acc[i][6] + bias[6]),
                                    __float2half_rn(acc[i][7] + bias[7]));
        *(__half2*)(xg + base + n_lo)     = p0;
        *(__half2*)(xg + base + n_lo + 2) = p1;
        *(__half2*)(xg + base + n_hi)     = p2;
        *(__half2*)(xg + base + n_hi + 2) = p3;
    }
}

// ---------------------------------------------------------------------------
// Zero the per-WG progress flags (ws is poisoned 0xAA before every launch).
// ---------------------------------------------------------------------------
__global__ void zero_cnt(unsigned* flags) {
    flags[threadIdx.x] = 0u;
}

// ---------------------------------------------------------------------------
// Phase B: persistent cooperative recurrence, flag-based sync (no wbl2!).
// 256 WGs (1/CU). WG = (r, c): r in [0,128) owns 6 hidden units (24 gate rows
// of W_hh resident in LDS for all 1024 steps), c in {0,1} picks a 16-batch
// group. Two independent domains of 128 WGs.
// Per step:
//   prefetch xg[t] (h-independent) -> poll 128 per-WG flags in parallel
//   (threads 0..127, sc1 loads) -> acquire fence (buffer_inv, cheap) ->
//   stage h_prev to LDS -> 12x4 register-tile dot, 32-way K-split -> LDS
//   reduce -> gates -> h stored with relaxed agent atomics (sc1 write-through,
//   nothing dirty in L2 => NO release/wbl2 fence) -> waitcnt+barrier ->
//   one relaxed flag store (flag = steps completed).
// c-state stays in registers of the 96 combine threads.
// ---------------------------------------------------------------------------
__global__ void __launch_bounds__(256, 1)
lstm_rec(const __half* __restrict__ xg, const float* __restrict__ Whh,
         float* __restrict__ out, unsigned* __restrict__ flags)
{
    extern __shared__ float sm[];
    float* Wsl = sm;                         // 24*768 = 18432 floats
    float* hsl = sm + 24 * H_SZ;             // 12288 floats (union with P)
    float* G   = sm + 24 * H_SZ + 12288;     // 384 floats

    const int tid = threadIdx.x;
    const int wg  = blockIdx.x;
    const int c   = wg & 1;        // batch group (sync domain)
    const int r   = wg >> 1;       // unit group 0..127
    const int u0  = r * 6;
    const int b0  = c * 16;

    // ---- load W_hh slice once: rows (gate*768 + u0 + j), gate<4, j<6 ----
    for (int i = tid; i < 24 * 192; i += 256) {
        const int rr = i / 192;              // local row 0..23
        const int kc = (i % 192) * 4;
        const int gate = rr / 6, j = rr % 6;
        const float4 v = *(const float4*)&Whh[(size_t)(gate * H_SZ + u0 + j) * H_SZ + kc];
        *(float4*)&Wsl[rr * H_SZ + kc] = v;
    }

    // dot-phase role
    const int ks     = tid & 31;             // K segment (k = 4*ks + 128*jj)
    const int tileId = tid >> 5;             // 0..7
    const int tr = (tileId & 1) * 12;        // row tile base
    const int tb = (tileId >> 1) * 4;        // batch tile base

    // combine-phase role (threads 0..95)
    const int cj = tid % 6;                  // unit within group
    const int cb = tid / 6;                  // batch within group
    float c_reg = 0.f;                       // cell state, register-resident

    unsigned* myflags = flags + c * 128;     // this domain's 128 flags

    // initial acquire: invalidate any stale clean lines (0xAA poison) for
    // the cached xg reads before the first per-step fence happens
    __builtin_amdgcn_fence(__ATOMIC_ACQUIRE, "agent");
    __syncthreads();

    for (int t = 0; t < T_LEN; ++t) {
        // ---- prefetch xg[t] for the combine (independent of h) ----
        float xpi = 0.f, xpf = 0.f, xpg = 0.f, xpo = 0.f;
        if (tid < 96) {
            const size_t xbase = ((size_t)t * B_SZ + (b0 + cb)) * G4 + u0 + cj;
            xpi = __half2float(xg[xbase + 0 * H_SZ]);
            xpf = __half2float(xg[xbase + 1 * H_SZ]);
            xpg = __half2float(xg[xbase + 2 * H_SZ]);
            xpo = __half2float(xg[xbase + 3 * H_SZ]);
        }

        if (t == 0) {
            for (int i = tid; i < 384; i += 256) G[i] = 0.f;  // h_prev = 0
            __syncthreads();
        } else {
            // ---- wait: all 128 WGs of this domain finished step t-1 ----
            if (tid < 128) {
                while (__hip_atomic_load(&myflags[tid], __ATOMIC_RELAXED,
                                         __HIP_MEMORY_SCOPE_AGENT) < (unsigned)t) {}
            }
            __syncthreads();
            __builtin_amdgcn_fence(__ATOMIC_ACQUIRE, "agent");  // inv stale lines

            // ---- stage h_prev[b0..b0+16][:] into LDS ----
            for (int i = tid; i < 16 * 192; i += 256) {
                const int b  = i / 192;
                const int kc = (i % 192) * 4;
                const float4 v = *(const float4*)&out[((size_t)(b0 + b) * T_LEN + (t - 1)) * H_SZ + kc];
                *(float4*)&hsl[b * H_SZ + kc] = v;
            }
            __syncthreads();

            // ---- dot: acc[12 rows][4 batches] over 24-element K segment ----
            float acc[12][4];
#pragma unroll
            for (int a = 0; a < 12; ++a)
#pragma unroll
                for (int q = 0; q < 4; ++q) acc[a][q] = 0.f;

            for (int jj = 0; jj < 6; ++jj) {
                const int k = ks * 4 + jj * 128;   // lanes stride-1 in k
                float4 hv[4];
#pragma unroll
                for (int q = 0; q < 4; ++q)
                    hv[q] = *(const float4*)&hsl[(tb + q) * H_SZ + k];
#pragma unroll
                for (int a = 0; a < 12; ++a) {
                    const float4 wv = *(const float4*)&Wsl[(tr + a) * H_SZ + k];
#pragma unroll
                    for (int q = 0; q < 4; ++q) {
                        acc[a][q] = fmaf(wv.x, hv[q].x, acc[a][q]);
                        acc[a][q] = fmaf(wv.y, hv[q].y, acc[a][q]);
                        acc[a][q] = fmaf(wv.z, hv[q].z, acc[a][q]);
                        acc[a][q] = fmaf(wv.w, hv[q].w, acc[a][q]);
                    }
                }
            }
            __syncthreads();                 // hsl reads done -> reuse as P

            // ---- write partials P[out 0..383][ks 0..31] ----
            float* P = hsl;
#pragma unroll
            for (int a = 0; a < 12; ++a)
#pragma unroll
                for (int q = 0; q < 4; ++q)
                    P[((tr + a) * 16 + (tb + q)) * 32 + ks] = acc[a][q];
            __syncthreads();

            // ---- reduce (diagonal reads: bank-conflict-free) ----
            for (int oi = tid; oi < 384; oi += 256) {
                float s = 0.f;
#pragma unroll
                for (int kk = 0; kk < 32; ++kk) {
                    const int k2 = (kk + oi) & 31;
                    s += P[oi * 32 + k2];
                }
                G[oi] = s;
            }
            __syncthreads();
        }

        // ---- gate combine: threads 0..95, one (unit, batch) each ----
        if (tid < 96) {
            const float pi = G[(0 * 6 + cj) * 16 + cb] + xpi;
            const float pf = G[(1 * 6 + cj) * 16 + cb] + xpf;
            const float pg = G[(2 * 6 + cj) * 16 + cb] + xpg;
            const float po = G[(3 * 6 + cj) * 16 + cb] + xpo;
            const float ig = 1.f / (1.f + __expf(-pi));
            const float fg = 1.f / (1.f + __expf(-pf));
            const float gg = tanhf(pg);
            const float og = 1.f / (1.f + __expf(-po));
            c_reg = fg * c_reg + ig * gg;
            const float h = og * tanhf(c_reg);
            // write-through to the device coherence point (sc0 sc1):
            // nothing dirty left in L2 -> no wbl2/release fence needed
            __hip_atomic_store(&out[((size_t)(b0 + cb) * T_LEN + t) * H_SZ + u0 + cj],
                               h, __ATOMIC_RELAXED, __HIP_MEMORY_SCOPE_AGENT);
        }
        // drain this wave's stores, then barrier so ALL waves' stores are done
        __builtin_amdgcn_s_waitcnt(0);
        __syncthreads();

        // ---- publish: one relaxed flag store (flag = steps completed) ----
        if (tid == 0) {
            __hip_atomic_store(&myflags[r], (unsigned)(t + 1), __ATOMIC_RELAXED,
                               __HIP_MEMORY_SCOPE_AGENT);
        }
    }
}

// ---------------------------------------------------------------------------
extern "C" void kernel_launch(void* const* d_in, const int* in_sizes, int n_in,
                              void* d_out, int out_size, void* d_ws, size_t ws_size,
                              hipStream_t stream)
{
    (void)in_sizes; (void)n_in; (void)out_size; (void)ws_size;
    const float* hidden = (const float*)d_in[0];
    const float* W_ih   = (const float*)d_in[1];
    const float* W_hh   = (const float*)d_in[2];
    const float* b_ih   = (const float*)d_in[3];
    const float* b_hh   = (const float*)d_in[4];
    float* out = (float*)d_out;

    __half* xg = (__half*)d_ws;                                  // 201,326,592 B
    unsigned* flags = (unsigned*)((char*)d_ws +
                      (size_t)T_LEN * B_SZ * G4 * sizeof(__half)); // 256 u32

    zero_cnt<<<dim3(1), dim3(256), 0, stream>>>(flags);
    xg_gemm<<<dim3(G4 / 128, (B_SZ * T_LEN) / 128), dim3(256), 0, stream>>>(
        hidden, W_ih, b_ih, b_hh, xg);

    const int smem = (24 * H_SZ + 12288 + 384) * (int)sizeof(float);  // 124,416 B
    hipFuncSetAttribute((const void*)lstm_rec,
                        hipFuncAttributeMaxDynamicSharedMemorySize, smem);
    void* args[] = { (void*)&xg, (void*)&W_hh, (void*)&out, (void*)&flags };
    hipLaunchCooperativeKernel((void*)lstm_rec, dim3(256), dim3(256),
                               args, (unsigned)smem, stream);
}

// Round 3
// 8220.609 us; speedup vs baseline: 3.1979x; 2.2730x over previous
//
#include <hip/hip_runtime.h>
#include <hip/hip_fp16.h>

#define T_LEN 1024
#define B_SZ  32
#define D_IN  768
#define H_SZ  768
#define G4    3072   // 4*H
#define FPAD  32     // flag padding: 1 flag per 128-byte line

// ---------------------------------------------------------------------------
// Phase A: xg[(t*32+b)][g] = hidden[b][t][:] . W_ih[g][:] + b_ih[g] + b_hh[g]
// fp32 SGEMM, 128x128 block, 8x8 microtile, output stored as fp16.
// (~1.9 ms measured — not the current bottleneck; unchanged.)
// ---------------------------------------------------------------------------
__global__ __launch_bounds__(256)
void xg_gemm(const float* __restrict__ hidden, const float* __restrict__ W_ih,
             const float* __restrict__ b_ih, const float* __restrict__ b_hh,
             __half* __restrict__ xg)
{
    __shared__ float As[8 * 128];
    __shared__ float Bs[8 * 128];
    const int tid = threadIdx.x;
    const int tx = tid & 15, ty = tid >> 4;
    const int n0 = blockIdx.x * 128;
    const int m0 = blockIdx.y * 128;

    const int lrow = tid >> 1;          // 0..127
    const int lk   = (tid & 1) * 4;     // 0 or 4

    const int m  = m0 + lrow;
    const int bb = m & 31;
    const int tt = m >> 5;
    const float* arow = hidden + ((size_t)bb * T_LEN + tt) * D_IN;
    const float* brow = W_ih + (size_t)(n0 + lrow) * D_IN;

    float acc[8][8];
#pragma unroll
    for (int i = 0; i < 8; ++i)
#pragma unroll
        for (int j = 0; j < 8; ++j) acc[i][j] = 0.f;

    for (int kb = 0; kb < D_IN; kb += 8) {
        const float4 av = *(const float4*)(arow + kb + lk);
        const float4 bv = *(const float4*)(brow + kb + lk);
        __syncthreads();
        As[(lk + 0) * 128 + lrow] = av.x;
        As[(lk + 1) * 128 + lrow] = av.y;
        As[(lk + 2) * 128 + lrow] = av.z;
        As[(lk + 3) * 128 + lrow] = av.w;
        Bs[(lk + 0) * 128 + lrow] = bv.x;
        Bs[(lk + 1) * 128 + lrow] = bv.y;
        Bs[(lk + 2) * 128 + lrow] = bv.z;
        Bs[(lk + 3) * 128 + lrow] = bv.w;
        __syncthreads();
#pragma unroll
        for (int k = 0; k < 8; ++k) {
            const float4 a0 = *(const float4*)&As[k * 128 + 4 * ty];
            const float4 a1 = *(const float4*)&As[k * 128 + 64 + 4 * ty];
            const float4 b0 = *(const float4*)&Bs[k * 128 + 4 * tx];
            const float4 b1 = *(const float4*)&Bs[k * 128 + 64 + 4 * tx];
            const float a[8] = {a0.x, a0.y, a0.z, a0.w, a1.x, a1.y, a1.z, a1.w};
            const float b[8] = {b0.x, b0.y, b0.z, b0.w, b1.x, b1.y, b1.z, b1.w};
#pragma unroll
            for (int i = 0; i < 8; ++i)
#pragma unroll
                for (int j = 0; j < 8; ++j)
                    acc[i][j] = fmaf(a[i], b[j], acc[i][j]);
        }
    }

    float bias[8];
    {
        const int n_lo = n0 + 4 * tx, n_hi = n0 + 64 + 4 * tx;
        const float4 bi0 = *(const float4*)(b_ih + n_lo);
        const float4 bh0 = *(const float4*)(b_hh + n_lo);
        const float4 bi1 = *(const float4*)(b_ih + n_hi);
        const float4 bh1 = *(const float4*)(b_hh + n_hi);
        bias[0] = bi0.x + bh0.x; bias[1] = bi0.y + bh0.y;
        bias[2] = bi0.z + bh0.z; bias[3] = bi0.w + bh0.w;
        bias[4] = bi1.x + bh1.x; bias[5] = bi1.y + bh1.y;
        bias[6] = bi1.z + bh1.z; bias[7] = bi1.w + bh1.w;
    }

#pragma unroll
    for (int i = 0; i < 8; ++i) {
        const int mm = m0 + ((i < 4) ? (4 * ty + i) : (64 + 4 * ty + (i - 4)));
        const size_t base = (size_t)mm * G4;
        const int n_lo = n0 + 4 * tx, n_hi = n0 + 64 + 4 * tx;
        __half2 p0 = __halves2half2(__float2half_rn(acc[i][0] + bias[0]),
                                    __float2half_rn(acc[i][1] + bias[1]));
        __half2 p1 = __halves2half2(__float2half_rn(acc[i][2] + bias[2]),
                                    __float2half_rn(acc[i][3] + bias[3]));
        __half2 p2 = __halves2half2(__float2half_rn(acc[i][4] + bias[4]),
                                    __float2half_rn(acc[i][5] + bias[5]));
        __half2 p3 = __halves2half2(__float2half_rn(acc[i][6] + bias[6]),
                                    __float2half_rn(acc[i][7] + bias[7]));
        *(__half2*)(xg + base + n_lo)     = p0;
        *(__half2*)(xg + base + n_lo + 2) = p1;
        *(__half2*)(xg + base + n_hi)     = p2;
        *(__half2*)(xg + base + n_hi + 2) = p3;
    }
}

// ---------------------------------------------------------------------------
// Zero the padded per-WG progress flags (2 domains x 128 flags x 32 stride).
// ---------------------------------------------------------------------------
__global__ void zero_cnt(unsigned* flags) {
    flags[blockIdx.x * 1024 + threadIdx.x] = 0u;
}

// ---------------------------------------------------------------------------
// Phase B: persistent cooperative recurrence.
// Sync design (R3): per-WG progress flags, ONE PER 128-B CACHE LINE (no
// same-line writer serialization, no hot-line poll contention). NO per-step
// acquire fence: h is read with relaxed agent-scope atomic dword loads
// (coherence-point bypass), so nobody invalidates anybody's L1/L2 and xg/out
// lines stay cached. Producer: h stores are relaxed agent atomics
// (write-through), drained with a targeted s_waitcnt vmcnt(0) before the
// flag store.
// ---------------------------------------------------------------------------
__global__ void __launch_bounds__(256, 1)
lstm_rec(const __half* __restrict__ xg, const float* __restrict__ Whh,
         float* __restrict__ out, unsigned* __restrict__ flags)
{
    extern __shared__ float sm[];
    float* Wsl = sm;                         // 24*768 = 18432 floats
    float* hsl = sm + 24 * H_SZ;             // 12288 floats (union with P)
    float* G   = sm + 24 * H_SZ + 12288;     // 384 floats

    const int tid = threadIdx.x;
    const int wg  = blockIdx.x;
    const int c   = wg & 1;        // batch group (sync domain)
    const int r   = wg >> 1;       // unit group 0..127
    const int u0  = r * 6;
    const int b0  = c * 16;

    // ---- load W_hh slice once: rows (gate*768 + u0 + j), gate<4, j<6 ----
    for (int i = tid; i < 24 * 192; i += 256) {
        const int rr = i / 192;              // local row 0..23
        const int kc = (i % 192) * 4;
        const int gate = rr / 6, j = rr % 6;
        const float4 v = *(const float4*)&Whh[(size_t)(gate * H_SZ + u0 + j) * H_SZ + kc];
        *(float4*)&Wsl[rr * H_SZ + kc] = v;
    }

    // dot-phase role
    const int ks     = tid & 31;             // K segment (k = 4*ks + 128*jj)
    const int tileId = tid >> 5;             // 0..7
    const int tr = (tileId & 1) * 12;        // row tile base
    const int tb = (tileId >> 1) * 4;        // batch tile base

    // combine-phase role (threads 0..95)
    const int cj = tid % 6;                  // unit within group
    const int cb = tid / 6;                  // batch within group
    float c_reg = 0.f;                       // cell state, register-resident

    unsigned* myflags = flags + c * 128 * FPAD;

    __builtin_amdgcn_fence(__ATOMIC_ACQUIRE, "agent");  // once: clear poison
    __syncthreads();

    for (int t = 0; t < T_LEN; ++t) {
        // ---- prefetch xg[t] for the combine (independent of h) ----
        float xpi = 0.f, xpf = 0.f, xpg = 0.f, xpo = 0.f;
        if (tid < 96) {
            const size_t xbase = ((size_t)t * B_SZ + (b0 + cb)) * G4 + u0 + cj;
            xpi = __half2float(xg[xbase + 0 * H_SZ]);
            xpf = __half2float(xg[xbase + 1 * H_SZ]);
            xpg = __half2float(xg[xbase + 2 * H_SZ]);
            xpo = __half2float(xg[xbase + 3 * H_SZ]);
        }

        if (t == 0) {
            for (int i = tid; i < 384; i += 256) G[i] = 0.f;  // h_prev = 0
            __syncthreads();
        } else {
            // ---- wait: all 128 WGs of this domain finished step t-1 ----
            if (tid < 128) {
                while (__hip_atomic_load(&myflags[tid * FPAD], __ATOMIC_RELAXED,
                                         __HIP_MEMORY_SCOPE_AGENT) < (unsigned)t) {}
            }
            __syncthreads();

            // ---- stage h_prev[b0..b0+16][:] into LDS via coherent dword
            //      loads (no fence needed). b = i/3, k = tid + (i%3)*256. ----
            float hreg[48];
#pragma unroll
            for (int i = 0; i < 48; ++i) {
                const int b = i / 3;
                const int k = tid + (i % 3) * 256;
                hreg[i] = __hip_atomic_load(
                    &out[((size_t)(b0 + b) * T_LEN + (t - 1)) * H_SZ + k],
                    __ATOMIC_RELAXED, __HIP_MEMORY_SCOPE_AGENT);
            }
#pragma unroll
            for (int i = 0; i < 48; ++i) {
                const int b = i / 3;
                const int k = tid + (i % 3) * 256;
                hsl[b * H_SZ + k] = hreg[i];
            }
            __syncthreads();

            // ---- dot: acc[12 rows][4 batches] over 24-element K segment ----
            float acc[12][4];
#pragma unroll
            for (int a = 0; a < 12; ++a)
#pragma unroll
                for (int q = 0; q < 4; ++q) acc[a][q] = 0.f;

            for (int jj = 0; jj < 6; ++jj) {
                const int k = ks * 4 + jj * 128;   // lanes stride-1 in k
                float4 hv[4];
#pragma unroll
                for (int q = 0; q < 4; ++q)
                    hv[q] = *(const float4*)&hsl[(tb + q) * H_SZ + k];
#pragma unroll
                for (int a = 0; a < 12; ++a) {
                    const float4 wv = *(const float4*)&Wsl[(tr + a) * H_SZ + k];
#pragma unroll
                    for (int q = 0; q < 4; ++q) {
                        acc[a][q] = fmaf(wv.x, hv[q].x, acc[a][q]);
                        acc[a][q] = fmaf(wv.y, hv[q].y, acc[a][q]);
                        acc[a][q] = fmaf(wv.z, hv[q].z, acc[a][q]);
                        acc[a][q] = fmaf(wv.w, hv[q].w, acc[a][q]);
                    }
                }
            }
            __syncthreads();                 // hsl reads done -> reuse as P

            // ---- write partials P[out 0..383][ks 0..31] ----
            float* P = hsl;
#pragma unroll
            for (int a = 0; a < 12; ++a)
#pragma unroll
                for (int q = 0; q < 4; ++q)
                    P[((tr + a) * 16 + (tb + q)) * 32 + ks] = acc[a][q];
            __syncthreads();

            // ---- reduce (diagonal reads: bank-conflict-free) ----
            for (int oi = tid; oi < 384; oi += 256) {
                float s = 0.f;
#pragma unroll
                for (int kk = 0; kk < 32; ++kk) {
                    const int k2 = (kk + oi) & 31;
                    s += P[oi * 32 + k2];
                }
                G[oi] = s;
            }
            __syncthreads();
        }

        // ---- gate combine: threads 0..95, one (unit, batch) each ----
        if (tid < 96) {
            const float pi = G[(0 * 6 + cj) * 16 + cb] + xpi;
            const float pf = G[(1 * 6 + cj) * 16 + cb] + xpf;
            const float pg = G[(2 * 6 + cj) * 16 + cb] + xpg;
            const float po = G[(3 * 6 + cj) * 16 + cb] + xpo;
            const float ig = 1.f / (1.f + __expf(-pi));
            const float fg = 1.f / (1.f + __expf(-pf));
            const float gg = tanhf(pg);
            const float og = 1.f / (1.f + __expf(-po));
            c_reg = fg * c_reg + ig * gg;
            const float h = og * tanhf(c_reg);
            // write-through to the device coherence point; readers bypass too
            __hip_atomic_store(&out[((size_t)(b0 + cb) * T_LEN + t) * H_SZ + u0 + cj],
                               h, __ATOMIC_RELAXED, __HIP_MEMORY_SCOPE_AGENT);
        }
        // drain only vmem stores, then barrier so ALL waves' stores are done
        asm volatile("s_waitcnt vmcnt(0)" ::: "memory");
        __syncthreads();

        // ---- publish: one relaxed flag store (flag = steps completed) ----
        if (tid == 0) {
            __hip_atomic_store(&myflags[r * FPAD], (unsigned)(t + 1),
                               __ATOMIC_RELAXED, __HIP_MEMORY_SCOPE_AGENT);
        }
    }
}

// ---------------------------------------------------------------------------
extern "C" void kernel_launch(void* const* d_in, const int* in_sizes, int n_in,
                              void* d_out, int out_size, void* d_ws, size_t ws_size,
                              hipStream_t stream)
{
    (void)in_sizes; (void)n_in; (void)out_size; (void)ws_size;
    const float* hidden = (const float*)d_in[0];
    const float* W_ih   = (const float*)d_in[1];
    const float* W_hh   = (const float*)d_in[2];
    const float* b_ih   = (const float*)d_in[3];
    const float* b_hh   = (const float*)d_in[4];
    float* out = (float*)d_out;

    __half* xg = (__half*)d_ws;                                  // 201,326,592 B
    unsigned* flags = (unsigned*)((char*)d_ws +
                      (size_t)T_LEN * B_SZ * G4 * sizeof(__half)); // 8192 u32

    zero_cnt<<<dim3(8), dim3(1024), 0, stream>>>(flags);
    xg_gemm<<<dim3(G4 / 128, (B_SZ * T_LEN) / 128), dim3(256), 0, stream>>>(
        hidden, W_ih, b_ih, b_hh, xg);

    const int smem = (24 * H_SZ + 12288 + 384) * (int)sizeof(float);  // 124,416 B
    hipFuncSetAttribute((const void*)lstm_rec,
                        hipFuncAttributeMaxDynamicSharedMemorySize, smem);
    void* args[] = { (void*)&xg, (void*)&W_hh, (void*)&out, (void*)&flags };
    hipLaunchCooperativeKernel((void*)lstm_rec, dim3(256), dim3(256),
                               args, (unsigned)smem, stream);
}